// Round 4
// baseline (345.850 us; speedup 1.0000x reference)
//
#include <hip/hip_runtime.h>

#define B_   32
#define L_   512
#define S1_  513
#define LP_  16
#define NEG  (-1.0e9f)
#define NINF (-3.0e38f)
#define L2E  1.4426950408889634f
#define LN2f 0.6931471805599453f

typedef unsigned short ushort_t;
typedef unsigned int   uint_t;

#if defined(__has_builtin)
#if __has_builtin(__builtin_amdgcn_fdot2_f32_bf16)
#define HAS_DOT2 1
#endif
#endif

#ifdef HAS_DOT2
typedef __bf16 bf16x2_t __attribute__((ext_vector_type(2)));
#endif

__device__ __forceinline__ float bf2f(ushort_t u) {
  return __uint_as_float(((uint_t)u) << 16);
}
__device__ __forceinline__ ushort_t f2bf(float f) {
  uint_t u = __float_as_uint(f);
  uint_t r = (u + 0x7FFFu + ((u >> 16) & 1u)) >> 16;
  return (ushort_t)r;
}
// packed 2xbf16 dot with f32 accumulate
__device__ __forceinline__ float dot2p(uint_t e, uint_t w, float c) {
#ifdef HAS_DOT2
  return __builtin_amdgcn_fdot2_f32_bf16(__builtin_bit_cast(bf16x2_t, e),
                                         __builtin_bit_cast(bf16x2_t, w), c, false);
#else
  return fmaf(__uint_as_float(e & 0xffff0000u), __uint_as_float(w & 0xffff0000u),
              fmaf(__uint_as_float(e << 16), __uint_as_float(w << 16), c));
#endif
}

// ---------------- setup kernels ----------------

__global__ void k_cumsum(const float* __restrict__ ss3, float* __restrict__ cs) {
  int b = blockIdx.x, c = blockIdx.y;
  __shared__ float buf[L_];
  int t = threadIdx.x;
  buf[t] = logf(ss3[(b * 3 + c) * L_ + t]);
  __syncthreads();
  for (int d = 1; d < L_; d <<= 1) {
    float add = (t >= d) ? buf[t - d] : 0.0f;
    __syncthreads();
    buf[t] += add;
    __syncthreads();
  }
  float* out = cs + (b * 3 + c) * S1_;
  if (t == 0) out[0] = 0.0f;
  out[t + 1] = buf[t];
}

// Build packed-oct layouts of E = exp(Q):
//  Efo[(c*64+jo)*513 + k] : uint4 = rows 8jo..8jo+7 (bf16) at column k
//  Ebo[(c*65+ko)*512 + j] : uint4 = cols 8ko..8ko+7 (bf16) at row j (cols>=513 padded 0)
__global__ void k_prep(const float* __restrict__ Q, uint4* __restrict__ Efo,
                       uint4* __restrict__ Ebo) {
  __shared__ float tile[64][65];
  const int kt = blockIdx.x;       // 0..8 (col tile; kt=8 has width 1)
  const int jt = blockIdx.y;       // 0..7 (row tile)
  const int c  = blockIdx.z;
  const int x = threadIdx.x;       // 0..63
  const int y = threadIdx.y;       // 0..7
  const float* q = Q + (size_t)c * S1_ * S1_;

  for (int rr = y; rr < 64; rr += 8) {
    int row = jt * 64 + rr;
    int col = kt * 64 + x;
    float e = 0.0f;
    if (col < S1_) e = expf(q[row * S1_ + col]);
    tile[rr][x] = e;
  }
  __syncthreads();

  // fwd-oct write: oct jo = jt*8+y, col = kt*64+x
  {
    int col = kt * 64 + x;
    if (col < S1_) {
      uint_t d0 = (uint_t)f2bf(tile[y * 8 + 0][x]) | ((uint_t)f2bf(tile[y * 8 + 1][x]) << 16);
      uint_t d1 = (uint_t)f2bf(tile[y * 8 + 2][x]) | ((uint_t)f2bf(tile[y * 8 + 3][x]) << 16);
      uint_t d2 = (uint_t)f2bf(tile[y * 8 + 4][x]) | ((uint_t)f2bf(tile[y * 8 + 5][x]) << 16);
      uint_t d3 = (uint_t)f2bf(tile[y * 8 + 6][x]) | ((uint_t)f2bf(tile[y * 8 + 7][x]) << 16);
      Efo[((size_t)c * 64 + jt * 8 + y) * 513 + col] = make_uint4(d0, d1, d2, d3);
    }
  }
  // bwd-oct write: oct ko = kt*8+y, row j = jt*64+x
  {
    int ko = kt * 8 + y;
    if (ko < 65) {
      uint_t d0 = (uint_t)f2bf(tile[x][y * 8 + 0]) | ((uint_t)f2bf(tile[x][y * 8 + 1]) << 16);
      uint_t d1 = (uint_t)f2bf(tile[x][y * 8 + 2]) | ((uint_t)f2bf(tile[x][y * 8 + 3]) << 16);
      uint_t d2 = (uint_t)f2bf(tile[x][y * 8 + 4]) | ((uint_t)f2bf(tile[x][y * 8 + 5]) << 16);
      uint_t d3 = (uint_t)f2bf(tile[x][y * 8 + 6]) | ((uint_t)f2bf(tile[x][y * 8 + 7]) << 16);
      Ebo[((size_t)c * 65 + ko) * 512 + jt * 64 + x] = make_uint4(d0, d1, d2, d3);
    }
  }
}

// ---------------- main scan kernel ----------------
// 64 blocks x 1024 threads: blockIdx.x = b*2 + dir.
__global__ __launch_bounds__(1024, 4) void k_scan(
    const uint4* __restrict__ Efo, const uint4* __restrict__ Ebo,
    const float* __restrict__ cs, const int* __restrict__ pattern,
    const int* __restrict__ ls,
    float* __restrict__ a_buf, float* __restrict__ b_buf) {
  const int b   = blockIdx.x >> 1;
  const int dir = blockIdx.x & 1;
  const int tid = threadIdx.x;
  const bool pri = tid < 512;
  const int ptid = pri ? tid : tid - 512;
  const int lane = ptid & 63;
  const int w    = ptid >> 6;
  const int tile = (w < 4) ? w : (11 - w);   // SIMD pairing: tiles t and 7-t share a SIMD
  const int myk  = tile * 64 + lane;         // 0..511

  __shared__ __align__(16) ushort_t wpk[512];   // bf16 w = exp2(z - tmax_tile)
  __shared__ float cs3[3 * S1_];
  __shared__ float zl[S1_];
  __shared__ float mshl[512];
  __shared__ float psum[512];
  __shared__ float tmaxs[9];                 // [8] = z512 (bwd)
  __shared__ float red[8];
  __shared__ int   pat[LP_];

  for (int i = tid; i < 3 * S1_; i += 1024) cs3[i] = cs[b * 3 * S1_ + i];
  if (tid < LP_) pat[tid] = pattern[tid];
  const int myls = ls[b];

  float* obuf = dir ? b_buf : a_buf;
  float areg = NEG, areg512 = NEG;
  if (pri) {
    const int initk = dir ? myls : 0;
    areg    = (myk == initk) ? 0.0f : NEG;
    areg512 = (dir && myls == 512) ? 0.0f : NEG;
    const int row0 = dir ? LP_ : 0;
    float* orow = obuf + (b * (LP_ + 1) + row0) * S1_;
    orow[myk] = areg;
    if (tid == 0) orow[512] = areg512;
  }
  __syncthreads();

  for (int s = 0; s < LP_; ++s) {
    const int c = pat[dir ? (LP_ - 1 - s) : s];
    const float* csr = cs3 + c * S1_;
    const uint4* Ecf = Efo + (size_t)c * 64 * 513;
    const uint4* Ecb = Ebo + (size_t)c * 65 * 512;

    float pfx = NINF, tmax = 0.f, z = 0.f;
    if (pri) {
      // --- phase 1: z
      const float mycs = csr[myk];
      z = areg + (dir ? mycs : -mycs);
      zl[myk] = z;
      // --- phase 2: per-wave inclusive max scan + tile max
      pfx = z;
      if (!dir) {
        #pragma unroll
        for (int d = 1; d < 64; d <<= 1) {
          float o = __shfl_up(pfx, d);
          if (lane >= d) pfx = fmaxf(pfx, o);
        }
        tmax = __shfl(pfx, 63);
        if (lane == 63) tmaxs[tile] = pfx;
      } else {
        #pragma unroll
        for (int d = 1; d < 64; d <<= 1) {
          float o = __shfl_down(pfx, d);
          if (lane < 64 - d) pfx = fmaxf(pfx, o);
        }
        tmax = __shfl(pfx, 0);
        if (lane == 0) tmaxs[tile] = pfx;
        if (tid == 0) tmaxs[8] = areg512 + csr[512];
      }
    }
    __syncthreads();                               // barrier A

    float msh = 0.f;
    if (pri) {
      // --- phase 3: per-column shift msh; packed-bf16 w
      if (!dir) {
        float off = NINF;
        for (int t2 = 0; t2 < tile; ++t2) off = fmaxf(off, tmaxs[t2]);
        float p1 = __shfl_up(pfx, 1);
        msh = fmaxf((lane == 0) ? NINF : p1, off);
      } else {
        float off = tmaxs[8];
        for (int t2 = tile + 1; t2 < 8; ++t2) off = fmaxf(off, tmaxs[t2]);
        float p1 = __shfl_down(pfx, 1);
        msh = fmaxf((lane == 63) ? NINF : p1, off);
      }
      mshl[myk] = msh;
      wpk[myk] = f2bf(exp2f((z - tmax) * L2E));
    }
    __syncthreads();                               // barrier B
    if (!pri) msh = mshl[myk];

    const uint_t* wdw = (const uint_t*)wpk;

    // --- phase 4: triangular weighted sum (oct-packed), split pri/sec
    float acc = 0.0f;
    if (!dir) {
      const int t0 = pri ? 0 : 1;
      for (int t = t0; t < tile; t += 2) {
        const uint4* ep  = Ecf + (t * 8) * 513 + myk;
        const uint4* wv4 = (const uint4*)(wdw + t * 32);
        float s0 = 0.f, s1 = 0.f, s2 = 0.f, s3 = 0.f;
        #pragma unroll
        for (int q = 0; q < 8; ++q) {
          uint4 e  = ep[q * 513];
          uint4 wv = wv4[q];
          s0 = dot2p(e.x, wv.x, s0);
          s1 = dot2p(e.y, wv.y, s1);
          s2 = dot2p(e.z, wv.z, s2);
          s3 = dot2p(e.w, wv.w, s3);
        }
        acc += exp2f((tmaxs[t] - msh) * L2E) * ((s0 + s1) + (s2 + s3));
      }
      if (!pri) {
        // diagonal subtile, per-element f32 path: rows j = tile*64 + (8qo+r), live iff < lane
        const ushort_t* epu = (const ushort_t*)(Ecf + (tile * 8) * 513 + myk);
        const float* zp = zl + tile * 64;
        float bacc = 0.f;
        for (int qo = 0; qo < 8; ++qo) {
          const ushort_t* e8 = epu + qo * 513 * 8;
          #pragma unroll
          for (int r = 0; r < 8; ++r) {
            float a = (qo * 8 + r < lane) ? (zp[qo * 8 + r] - msh) : NEG;
            bacc += bf2f(e8[r]) * exp2f(a * L2E);
          }
        }
        psum[myk] = acc + bacc;
      } else {
        // k = 512 column (one j per primary thread)
        float msh512 = tmaxs[0];
        #pragma unroll
        for (int t2 = 1; t2 < 8; ++t2) msh512 = fmaxf(msh512, tmaxs[t2]);
        float e512 = bf2f(((const ushort_t*)(Ecf + (tid >> 3) * 513 + 512))[tid & 7]);
        float p = e512 * bf2f(wpk[tid]) * exp2f((tmaxs[tid >> 6] - msh512) * L2E);
        #pragma unroll
        for (int o = 1; o < 64; o <<= 1) p += __shfl_xor(p, o);
        if (lane == 0) red[w] = p;
      }
    } else {
      const int t0 = tile + (pri ? 1 : 2);
      for (int t = t0; t < 8; t += 2) {
        const uint4* ep  = Ecb + (t * 8) * 512 + myk;
        const uint4* wv4 = (const uint4*)(wdw + t * 32);
        float s0 = 0.f, s1 = 0.f, s2 = 0.f, s3 = 0.f;
        #pragma unroll
        for (int q = 0; q < 8; ++q) {
          uint4 e  = ep[q * 512];
          uint4 wv = wv4[q];
          s0 = dot2p(e.x, wv.x, s0);
          s1 = dot2p(e.y, wv.y, s1);
          s2 = dot2p(e.z, wv.z, s2);
          s3 = dot2p(e.w, wv.w, s3);
        }
        acc += exp2f((tmaxs[t] - msh) * L2E) * ((s0 + s1) + (s2 + s3));
      }
      if (!pri) {
        // diagonal subtile: cols k = tile*64 + (8qo+r), live iff > lane
        const ushort_t* epu = (const ushort_t*)(Ecb + (tile * 8) * 512 + myk);
        const float* zp = zl + tile * 64;
        float bacc = 0.f;
        for (int qo = 0; qo < 8; ++qo) {
          const ushort_t* e8 = epu + qo * 512 * 8;
          #pragma unroll
          for (int r = 0; r < 8; ++r) {
            float a = (qo * 8 + r > lane) ? (zp[qo * 8 + r] - msh) : NEG;
            bacc += bf2f(e8[r]) * exp2f(a * L2E);
          }
        }
        // k = 512 term (per-element, safe scale: z512 <= msh)
        bacc += bf2f(((const ushort_t*)(Ecb + 64 * 512 + myk))[0]) *
                exp2f((tmaxs[8] - msh) * L2E);
        psum[myk] = acc + bacc;
      }
    }
    __syncthreads();                               // barrier C

    if (pri) {
      acc += psum[myk];
      if (!dir) {
        float ar = (acc > 0.0f) ? (csr[myk] + msh + log2f(acc) * LN2f) : NEG;
        areg = ar;
        float* orow = obuf + (b * (LP_ + 1) + (s + 1)) * S1_;
        orow[myk] = ar;
        if (tid == 0) {
          float msh512 = tmaxs[0];
          #pragma unroll
          for (int t2 = 1; t2 < 8; ++t2) msh512 = fmaxf(msh512, tmaxs[t2]);
          float t2s = ((red[0] + red[1]) + (red[2] + red[3])) +
                      ((red[4] + red[5]) + (red[6] + red[7]));
          areg512 = (t2s > 0.0f) ? (csr[512] + msh512 + log2f(t2s) * LN2f) : NEG;
          orow[512] = areg512;
        }
      } else {
        float ar = (acc > 0.0f) ? (msh - csr[myk] + log2f(acc) * LN2f) : NEG;
        areg = ar;
        float* orow = obuf + (b * (LP_ + 1) + (LP_ - 1 - s)) * S1_;
        orow[myk] = ar;
        if (tid == 0) { areg512 = NEG; orow[512] = NEG; }
      }
    }
  }
}

// ---------------- epilogue ----------------
__global__ void k_out(const float* __restrict__ a_buf, const float* __restrict__ b_buf,
                      const int* __restrict__ ls, float* __restrict__ out) {
  const int TOT = B_ * (LP_ + 1) * S1_;
  int idx = blockIdx.x * 256 + threadIdx.x;
  if (idx >= TOT) return;
  int b = idx / ((LP_ + 1) * S1_);
  float M = a_buf[(b * (LP_ + 1) + LP_) * S1_ + ls[b]];
  out[idx] = a_buf[idx] + b_buf[idx] - M;
}

// ---------------- launcher ----------------
extern "C" void kernel_launch(void* const* d_in, const int* in_sizes, int n_in,
                              void* d_out, int out_size, void* d_ws, size_t ws_size,
                              hipStream_t stream) {
  const float* ss3     = (const float*)d_in[0];
  const float* Q       = (const float*)d_in[1];
  const int*   pattern = (const int*)d_in[2];
  const int*   ls      = (const int*)d_in[3];
  float* out = (float*)d_out;

  float* ws    = (float*)d_ws;
  float* cs    = ws;                                    // B*3*S1 floats
  float* a_buf = cs + B_ * 3 * S1_;                     // B*(LP+1)*S1
  float* b_buf = a_buf + B_ * (LP_ + 1) * S1_;
  uint4* Efo = (uint4*)(b_buf + B_ * (LP_ + 1) * S1_);  // 3*64*513 uint4 (16B-aligned)
  uint4* Ebo = Efo + 3 * 64 * 513;                      // 3*65*512 uint4

  k_cumsum<<<dim3(B_, 3), 512, 0, stream>>>(ss3, cs);
  k_prep  <<<dim3(9, 8, 3), dim3(64, 8), 0, stream>>>(Q, Efo, Ebo);
  k_scan  <<<2 * B_, 1024, 0, stream>>>(Efo, Ebo, cs, pattern, ls, a_buf, b_buf);

  const int TOT = B_ * (LP_ + 1) * S1_;
  k_out<<<(TOT + 255) / 256, 256, 0, stream>>>(a_buf, b_buf, ls, out);
}

// Round 5
// 344.190 us; speedup vs baseline: 1.0048x; 1.0048x over previous
//
#include <hip/hip_runtime.h>

#define B_   32
#define L_   512
#define S1_  513
#define LP_  16
#define NEG  (-1.0e9f)
#define NINF (-3.0e38f)
#define L2E  1.4426950408889634f
#define LN2f 0.6931471805599453f

typedef unsigned short ushort_t;
typedef unsigned int   uint_t;

#if defined(__has_builtin)
#if __has_builtin(__builtin_amdgcn_fdot2_f32_bf16)
#define HAS_DOT2 1
#endif
#endif

#ifdef HAS_DOT2
typedef __bf16 bf16x2_t __attribute__((ext_vector_type(2)));
#endif

__device__ __forceinline__ float bf2f(ushort_t u) {
  return __uint_as_float(((uint_t)u) << 16);
}
__device__ __forceinline__ ushort_t f2bf(float f) {
  uint_t u = __float_as_uint(f);
  uint_t r = (u + 0x7FFFu + ((u >> 16) & 1u)) >> 16;
  return (ushort_t)r;
}
// packed 2xbf16 dot with f32 accumulate
__device__ __forceinline__ float dot2p(uint_t e, uint_t w, float c) {
#ifdef HAS_DOT2
  return __builtin_amdgcn_fdot2_f32_bf16(__builtin_bit_cast(bf16x2_t, e),
                                         __builtin_bit_cast(bf16x2_t, w), c, false);
#else
  return fmaf(__uint_as_float(e & 0xffff0000u), __uint_as_float(w & 0xffff0000u),
              fmaf(__uint_as_float(e << 16), __uint_as_float(w << 16), c));
#endif
}

// ---------------- setup kernels ----------------

__global__ void k_cumsum(const float* __restrict__ ss3, float* __restrict__ cs) {
  int b = blockIdx.x, c = blockIdx.y;
  __shared__ float buf[L_];
  int t = threadIdx.x;
  buf[t] = logf(ss3[(b * 3 + c) * L_ + t]);
  __syncthreads();
  for (int d = 1; d < L_; d <<= 1) {
    float add = (t >= d) ? buf[t - d] : 0.0f;
    __syncthreads();
    buf[t] += add;
    __syncthreads();
  }
  float* out = cs + (b * 3 + c) * S1_;
  if (t == 0) out[0] = 0.0f;
  out[t + 1] = buf[t];
}

// Build packed-oct layouts of E = exp(Q):
//  Efo[(c*64+jo)*513 + k] : uint4 = rows 8jo..8jo+7 (bf16) at column k
//  Ebo[(c*65+ko)*512 + j] : uint4 = cols 8ko..8ko+7 (bf16) at row j (cols>=513 padded 0)
__global__ void k_prep(const float* __restrict__ Q, uint4* __restrict__ Efo,
                       uint4* __restrict__ Ebo) {
  __shared__ float tile[64][65];
  const int kt = blockIdx.x;       // 0..8 (col tile; kt=8 has width 1)
  const int jt = blockIdx.y;       // 0..7 (row tile)
  const int c  = blockIdx.z;
  const int x = threadIdx.x;       // 0..63
  const int y = threadIdx.y;       // 0..7
  const float* q = Q + (size_t)c * S1_ * S1_;

  for (int rr = y; rr < 64; rr += 8) {
    int row = jt * 64 + rr;
    int col = kt * 64 + x;
    float e = 0.0f;
    if (col < S1_) e = expf(q[row * S1_ + col]);
    tile[rr][x] = e;
  }
  __syncthreads();

  // fwd-oct write: oct jo = jt*8+y, col = kt*64+x
  {
    int col = kt * 64 + x;
    if (col < S1_) {
      uint_t d0 = (uint_t)f2bf(tile[y * 8 + 0][x]) | ((uint_t)f2bf(tile[y * 8 + 1][x]) << 16);
      uint_t d1 = (uint_t)f2bf(tile[y * 8 + 2][x]) | ((uint_t)f2bf(tile[y * 8 + 3][x]) << 16);
      uint_t d2 = (uint_t)f2bf(tile[y * 8 + 4][x]) | ((uint_t)f2bf(tile[y * 8 + 5][x]) << 16);
      uint_t d3 = (uint_t)f2bf(tile[y * 8 + 6][x]) | ((uint_t)f2bf(tile[y * 8 + 7][x]) << 16);
      Efo[((size_t)c * 64 + jt * 8 + y) * 513 + col] = make_uint4(d0, d1, d2, d3);
    }
  }
  // bwd-oct write: oct ko = kt*8+y, row j = jt*64+x
  {
    int ko = kt * 8 + y;
    if (ko < 65) {
      uint_t d0 = (uint_t)f2bf(tile[x][y * 8 + 0]) | ((uint_t)f2bf(tile[x][y * 8 + 1]) << 16);
      uint_t d1 = (uint_t)f2bf(tile[x][y * 8 + 2]) | ((uint_t)f2bf(tile[x][y * 8 + 3]) << 16);
      uint_t d2 = (uint_t)f2bf(tile[x][y * 8 + 4]) | ((uint_t)f2bf(tile[x][y * 8 + 5]) << 16);
      uint_t d3 = (uint_t)f2bf(tile[x][y * 8 + 6]) | ((uint_t)f2bf(tile[x][y * 8 + 7]) << 16);
      Ebo[((size_t)c * 65 + ko) * 512 + jt * 64 + x] = make_uint4(d0, d1, d2, d3);
    }
  }
}

// ---------------- main scan kernel ----------------
// 64 blocks x 1024 threads. XCD-segregated mapping (XCD = blockIdx%8 heuristic):
// dir = bit2 of blockIdx -> XCDs 0-3 run forward (read Efo only),
// XCDs 4-7 run backward (read Ebo only). Halves per-XCD L2 working set.
__global__ __launch_bounds__(1024, 4) void k_scan(
    const uint4* __restrict__ Efo, const uint4* __restrict__ Ebo,
    const float* __restrict__ cs, const int* __restrict__ pattern,
    const int* __restrict__ ls,
    float* __restrict__ a_buf, float* __restrict__ b_buf) {
  const int dir = (blockIdx.x >> 2) & 1;
  const int b   = ((blockIdx.x >> 3) << 2) | (blockIdx.x & 3);
  const int tid = threadIdx.x;
  const bool pri = tid < 512;
  const int ptid = pri ? tid : tid - 512;
  const int lane = ptid & 63;
  const int w    = ptid >> 6;
  const int tile = (w < 4) ? w : (11 - w);   // SIMD pairing: tiles t and 7-t share a SIMD
  const int myk  = tile * 64 + lane;         // 0..511

  __shared__ __align__(16) ushort_t wpk[512];   // bf16 w = exp2(z - tmax_tile)
  __shared__ float cs3[3 * S1_];
  __shared__ float zl[S1_];
  __shared__ float mshl[512];
  __shared__ float psum[512];
  __shared__ float tmaxs[9];                 // [8] = z512 (bwd)
  __shared__ float red[8];
  __shared__ int   pat[LP_];

  for (int i = tid; i < 3 * S1_; i += 1024) cs3[i] = cs[b * 3 * S1_ + i];
  if (tid < LP_) pat[tid] = pattern[tid];
  const int myls = ls[b];

  float* obuf = dir ? b_buf : a_buf;
  float areg = NEG, areg512 = NEG;
  if (pri) {
    const int initk = dir ? myls : 0;
    areg    = (myk == initk) ? 0.0f : NEG;
    areg512 = (dir && myls == 512) ? 0.0f : NEG;
    const int row0 = dir ? LP_ : 0;
    float* orow = obuf + (b * (LP_ + 1) + row0) * S1_;
    orow[myk] = areg;
    if (tid == 0) orow[512] = areg512;
  }
  __syncthreads();

  for (int s = 0; s < LP_; ++s) {
    const int c = pat[dir ? (LP_ - 1 - s) : s];
    const float* csr = cs3 + c * S1_;
    const uint4* Ecf = Efo + (size_t)c * 64 * 513;
    const uint4* Ecb = Ebo + (size_t)c * 65 * 512;

    float pfx = NINF, tmax = 0.f, z = 0.f;
    if (pri) {
      // --- phase 1: z
      const float mycs = csr[myk];
      z = areg + (dir ? mycs : -mycs);
      zl[myk] = z;
      // --- phase 2: per-wave inclusive max scan + tile max
      pfx = z;
      if (!dir) {
        #pragma unroll
        for (int d = 1; d < 64; d <<= 1) {
          float o = __shfl_up(pfx, d);
          if (lane >= d) pfx = fmaxf(pfx, o);
        }
        tmax = __shfl(pfx, 63);
        if (lane == 63) tmaxs[tile] = pfx;
      } else {
        #pragma unroll
        for (int d = 1; d < 64; d <<= 1) {
          float o = __shfl_down(pfx, d);
          if (lane < 64 - d) pfx = fmaxf(pfx, o);
        }
        tmax = __shfl(pfx, 0);
        if (lane == 0) tmaxs[tile] = pfx;
        if (tid == 0) tmaxs[8] = areg512 + csr[512];
      }
    }
    __syncthreads();                               // barrier A

    float msh = 0.f;
    if (pri) {
      // --- phase 3: per-column shift msh; packed-bf16 w
      if (!dir) {
        float off = NINF;
        for (int t2 = 0; t2 < tile; ++t2) off = fmaxf(off, tmaxs[t2]);
        float p1 = __shfl_up(pfx, 1);
        msh = fmaxf((lane == 0) ? NINF : p1, off);
      } else {
        float off = tmaxs[8];
        for (int t2 = tile + 1; t2 < 8; ++t2) off = fmaxf(off, tmaxs[t2]);
        float p1 = __shfl_down(pfx, 1);
        msh = fmaxf((lane == 63) ? NINF : p1, off);
      }
      mshl[myk] = msh;
      wpk[myk] = f2bf(exp2f((z - tmax) * L2E));
    }
    __syncthreads();                               // barrier B
    if (!pri) msh = mshl[myk];

    const uint_t* wdw = (const uint_t*)wpk;

    // --- phase 4: triangular weighted sum (oct-packed), split pri/sec
    float acc = 0.0f;
    if (!dir) {
      const int t0 = pri ? 0 : 1;
      for (int t = t0; t < tile; t += 2) {
        const uint4* ep  = Ecf + (t * 8) * 513 + myk;
        const uint4* wv4 = (const uint4*)(wdw + t * 32);
        float s0 = 0.f, s1 = 0.f, s2 = 0.f, s3 = 0.f;
        #pragma unroll
        for (int q = 0; q < 8; ++q) {
          uint4 e  = ep[q * 513];
          uint4 wv = wv4[q];
          s0 = dot2p(e.x, wv.x, s0);
          s1 = dot2p(e.y, wv.y, s1);
          s2 = dot2p(e.z, wv.z, s2);
          s3 = dot2p(e.w, wv.w, s3);
        }
        acc += exp2f((tmaxs[t] - msh) * L2E) * ((s0 + s1) + (s2 + s3));
      }
      if (!pri) {
        // diagonal subtile, per-element f32 path: rows j = tile*64 + (8qo+r), live iff < lane
        const ushort_t* epu = (const ushort_t*)(Ecf + (tile * 8) * 513 + myk);
        const float* zp = zl + tile * 64;
        float bacc = 0.f;
        for (int qo = 0; qo < 8; ++qo) {
          const ushort_t* e8 = epu + qo * 513 * 8;
          #pragma unroll
          for (int r = 0; r < 8; ++r) {
            float a = (qo * 8 + r < lane) ? (zp[qo * 8 + r] - msh) : NEG;
            bacc += bf2f(e8[r]) * exp2f(a * L2E);
          }
        }
        psum[myk] = acc + bacc;
      } else {
        // k = 512 column (one j per primary thread)
        float msh512 = tmaxs[0];
        #pragma unroll
        for (int t2 = 1; t2 < 8; ++t2) msh512 = fmaxf(msh512, tmaxs[t2]);
        float e512 = bf2f(((const ushort_t*)(Ecf + (tid >> 3) * 513 + 512))[tid & 7]);
        float p = e512 * bf2f(wpk[tid]) * exp2f((tmaxs[tid >> 6] - msh512) * L2E);
        #pragma unroll
        for (int o = 1; o < 64; o <<= 1) p += __shfl_xor(p, o);
        if (lane == 0) red[w] = p;
      }
    } else {
      const int t0 = tile + (pri ? 1 : 2);
      for (int t = t0; t < 8; t += 2) {
        const uint4* ep  = Ecb + (t * 8) * 512 + myk;
        const uint4* wv4 = (const uint4*)(wdw + t * 32);
        float s0 = 0.f, s1 = 0.f, s2 = 0.f, s3 = 0.f;
        #pragma unroll
        for (int q = 0; q < 8; ++q) {
          uint4 e  = ep[q * 512];
          uint4 wv = wv4[q];
          s0 = dot2p(e.x, wv.x, s0);
          s1 = dot2p(e.y, wv.y, s1);
          s2 = dot2p(e.z, wv.z, s2);
          s3 = dot2p(e.w, wv.w, s3);
        }
        acc += exp2f((tmaxs[t] - msh) * L2E) * ((s0 + s1) + (s2 + s3));
      }
      if (!pri) {
        // diagonal subtile: cols k = tile*64 + (8qo+r), live iff > lane
        const ushort_t* epu = (const ushort_t*)(Ecb + (tile * 8) * 512 + myk);
        const float* zp = zl + tile * 64;
        float bacc = 0.f;
        for (int qo = 0; qo < 8; ++qo) {
          const ushort_t* e8 = epu + qo * 512 * 8;
          #pragma unroll
          for (int r = 0; r < 8; ++r) {
            float a = (qo * 8 + r > lane) ? (zp[qo * 8 + r] - msh) : NEG;
            bacc += bf2f(e8[r]) * exp2f(a * L2E);
          }
        }
        // k = 512 term (per-element, safe scale: z512 <= msh)
        bacc += bf2f(((const ushort_t*)(Ecb + 64 * 512 + myk))[0]) *
                exp2f((tmaxs[8] - msh) * L2E);
        psum[myk] = acc + bacc;
      }
    }
    __syncthreads();                               // barrier C

    if (pri) {
      acc += psum[myk];
      if (!dir) {
        float ar = (acc > 0.0f) ? (csr[myk] + msh + log2f(acc) * LN2f) : NEG;
        areg = ar;
        float* orow = obuf + (b * (LP_ + 1) + (s + 1)) * S1_;
        orow[myk] = ar;
        if (tid == 0) {
          float msh512 = tmaxs[0];
          #pragma unroll
          for (int t2 = 1; t2 < 8; ++t2) msh512 = fmaxf(msh512, tmaxs[t2]);
          float t2s = ((red[0] + red[1]) + (red[2] + red[3])) +
                      ((red[4] + red[5]) + (red[6] + red[7]));
          areg512 = (t2s > 0.0f) ? (csr[512] + msh512 + log2f(t2s) * LN2f) : NEG;
          orow[512] = areg512;
        }
      } else {
        float ar = (acc > 0.0f) ? (msh - csr[myk] + log2f(acc) * LN2f) : NEG;
        areg = ar;
        float* orow = obuf + (b * (LP_ + 1) + (LP_ - 1 - s)) * S1_;
        orow[myk] = ar;
        if (tid == 0) { areg512 = NEG; orow[512] = NEG; }
      }
    }
  }
}

// ---------------- epilogue ----------------
__global__ void k_out(const float* __restrict__ a_buf, const float* __restrict__ b_buf,
                      const int* __restrict__ ls, float* __restrict__ out) {
  const int TOT = B_ * (LP_ + 1) * S1_;
  int idx = blockIdx.x * 256 + threadIdx.x;
  if (idx >= TOT) return;
  int b = idx / ((LP_ + 1) * S1_);
  float M = a_buf[(b * (LP_ + 1) + LP_) * S1_ + ls[b]];
  out[idx] = a_buf[idx] + b_buf[idx] - M;
}

// ---------------- launcher ----------------
extern "C" void kernel_launch(void* const* d_in, const int* in_sizes, int n_in,
                              void* d_out, int out_size, void* d_ws, size_t ws_size,
                              hipStream_t stream) {
  const float* ss3     = (const float*)d_in[0];
  const float* Q       = (const float*)d_in[1];
  const int*   pattern = (const int*)d_in[2];
  const int*   ls      = (const int*)d_in[3];
  float* out = (float*)d_out;

  float* ws    = (float*)d_ws;
  float* cs    = ws;                                    // B*3*S1 floats
  float* a_buf = cs + B_ * 3 * S1_;                     // B*(LP+1)*S1
  float* b_buf = a_buf + B_ * (LP_ + 1) * S1_;
  uint4* Efo = (uint4*)(b_buf + B_ * (LP_ + 1) * S1_);  // 3*64*513 uint4 (16B-aligned)
  uint4* Ebo = Efo + 3 * 64 * 513;                      // 3*65*512 uint4

  k_cumsum<<<dim3(B_, 3), 512, 0, stream>>>(ss3, cs);
  k_prep  <<<dim3(9, 8, 3), dim3(64, 8), 0, stream>>>(Q, Efo, Ebo);
  k_scan  <<<2 * B_, 1024, 0, stream>>>(Efo, Ebo, cs, pattern, ls, a_buf, b_buf);

  const int TOT = B_ * (LP_ + 1) * S1_;
  k_out<<<(TOT + 255) / 256, 256, 0, stream>>>(a_buf, b_buf, ls, out);
}

// Round 6
// 315.332 us; speedup vs baseline: 1.0968x; 1.0915x over previous
//
#include <hip/hip_runtime.h>

#define B_   32
#define L_   512
#define S1_  513
#define LP_  16
#define NEG  (-1.0e9f)
#define NINF (-3.0e38f)
#define L2E  1.4426950408889634f
#define LN2f 0.6931471805599453f

typedef unsigned short ushort_t;
typedef unsigned int   uint_t;

#if defined(__has_builtin)
#if __has_builtin(__builtin_amdgcn_fdot2_f32_bf16)
#define HAS_DOT2 1
#endif
#if __has_builtin(__builtin_amdgcn_global_load_lds)
#define HAS_GLL 1
#endif
#endif

#ifdef HAS_DOT2
typedef __bf16 bf16x2_t __attribute__((ext_vector_type(2)));
#endif

__device__ __forceinline__ float bf2f(ushort_t u) {
  return __uint_as_float(((uint_t)u) << 16);
}
__device__ __forceinline__ ushort_t f2bf(float f) {
  uint_t u = __float_as_uint(f);
  uint_t r = (u + 0x7FFFu + ((u >> 16) & 1u)) >> 16;
  return (ushort_t)r;
}
__device__ __forceinline__ float dot2p(uint_t e, uint_t w, float c) {
#ifdef HAS_DOT2
  return __builtin_amdgcn_fdot2_f32_bf16(__builtin_bit_cast(bf16x2_t, e),
                                         __builtin_bit_cast(bf16x2_t, w), c, false);
#else
  return fmaf(__uint_as_float(e & 0xffff0000u), __uint_as_float(w & 0xffff0000u),
              fmaf(__uint_as_float(e << 16), __uint_as_float(w << 16), c));
#endif
}

// async global->LDS stage: lane i lands at lbase + i*16 (wave-uniform lbase)
__device__ __forceinline__ void stage16(const uint4* gsrc, uint4* lbase, int lane) {
#ifdef HAS_GLL
  __builtin_amdgcn_global_load_lds(
      (const __attribute__((address_space(1))) uint_t*)gsrc,
      (__attribute__((address_space(3))) uint_t*)lbase, 16, 0, 0);
#else
  lbase[lane] = *gsrc;   // synchronous fallback, same layout
#endif
}

__device__ __forceinline__ void wait_vm(int n) {
#ifdef HAS_GLL
  switch (n) {
    case 0: asm volatile("s_waitcnt vmcnt(0)" ::: "memory"); break;
    case 1: asm volatile("s_waitcnt vmcnt(1)" ::: "memory"); break;
    case 2: asm volatile("s_waitcnt vmcnt(2)" ::: "memory"); break;
    case 3: asm volatile("s_waitcnt vmcnt(3)" ::: "memory"); break;
    case 4: asm volatile("s_waitcnt vmcnt(4)" ::: "memory"); break;
    case 5: asm volatile("s_waitcnt vmcnt(5)" ::: "memory"); break;
    case 6: asm volatile("s_waitcnt vmcnt(6)" ::: "memory"); break;
    default: asm volatile("s_waitcnt vmcnt(7)" ::: "memory"); break;
  }
#endif
}

// raw barrier: flush own LDS ops, sync, fence compiler. vmcnt stays in flight.
__device__ __forceinline__ void sync_lgkm() {
  asm volatile("s_waitcnt lgkmcnt(0)" ::: "memory");
  __builtin_amdgcn_s_barrier();
  asm volatile("" ::: "memory");
}

// ---------------- setup kernels ----------------

__global__ void k_cumsum(const float* __restrict__ ss3, float* __restrict__ cs) {
  int b = blockIdx.x, c = blockIdx.y;
  __shared__ float buf[L_];
  int t = threadIdx.x;
  buf[t] = logf(ss3[(b * 3 + c) * L_ + t]);
  __syncthreads();
  for (int d = 1; d < L_; d <<= 1) {
    float add = (t >= d) ? buf[t - d] : 0.0f;
    __syncthreads();
    buf[t] += add;
    __syncthreads();
  }
  float* out = cs + (b * 3 + c) * S1_;
  if (t == 0) out[0] = 0.0f;
  out[t + 1] = buf[t];
}

// Efo[(c*64+jo)*513 + k] : uint4 = rows 8jo..8jo+7 (bf16 of exp Q) at column k
// Ebo[(c*65+ko)*512 + j] : uint4 = cols 8ko..8ko+7 at row j (cols>=513 padded 0)
__global__ void k_prep(const float* __restrict__ Q, uint4* __restrict__ Efo,
                       uint4* __restrict__ Ebo) {
  __shared__ float tile[64][65];
  const int kt = blockIdx.x;       // 0..8
  const int jt = blockIdx.y;       // 0..7
  const int c  = blockIdx.z;
  const int x = threadIdx.x;       // 0..63
  const int y = threadIdx.y;       // 0..7
  const float* q = Q + (size_t)c * S1_ * S1_;

  for (int rr = y; rr < 64; rr += 8) {
    int row = jt * 64 + rr;
    int col = kt * 64 + x;
    float e = 0.0f;
    if (col < S1_) e = expf(q[row * S1_ + col]);
    tile[rr][x] = e;
  }
  __syncthreads();
  {
    int col = kt * 64 + x;
    if (col < S1_) {
      uint_t d0 = (uint_t)f2bf(tile[y * 8 + 0][x]) | ((uint_t)f2bf(tile[y * 8 + 1][x]) << 16);
      uint_t d1 = (uint_t)f2bf(tile[y * 8 + 2][x]) | ((uint_t)f2bf(tile[y * 8 + 3][x]) << 16);
      uint_t d2 = (uint_t)f2bf(tile[y * 8 + 4][x]) | ((uint_t)f2bf(tile[y * 8 + 5][x]) << 16);
      uint_t d3 = (uint_t)f2bf(tile[y * 8 + 6][x]) | ((uint_t)f2bf(tile[y * 8 + 7][x]) << 16);
      Efo[((size_t)c * 64 + jt * 8 + y) * 513 + col] = make_uint4(d0, d1, d2, d3);
    }
  }
  {
    int ko = kt * 8 + y;
    if (ko < 65) {
      uint_t d0 = (uint_t)f2bf(tile[x][y * 8 + 0]) | ((uint_t)f2bf(tile[x][y * 8 + 1]) << 16);
      uint_t d1 = (uint_t)f2bf(tile[x][y * 8 + 2]) | ((uint_t)f2bf(tile[x][y * 8 + 3]) << 16);
      uint_t d2 = (uint_t)f2bf(tile[x][y * 8 + 4]) | ((uint_t)f2bf(tile[x][y * 8 + 5]) << 16);
      uint_t d3 = (uint_t)f2bf(tile[x][y * 8 + 6]) | ((uint_t)f2bf(tile[x][y * 8 + 7]) << 16);
      Ebo[((size_t)c * 65 + ko) * 512 + jt * 64 + x] = make_uint4(d0, d1, d2, d3);
    }
  }
}

// ---------------- main scan kernel ----------------
// 64 blocks x 1024 threads. Waves 0-7 primary, 8-15 secondary.
// Per-wave 8-slot x 1KB LDS ring staged by global_load_lds, counted vmcnt waits.
__global__ __launch_bounds__(1024) void k_scan(
    const uint4* __restrict__ Efo, const uint4* __restrict__ Ebo,
    const float* __restrict__ cs, const int* __restrict__ pattern,
    const int* __restrict__ ls,
    float* __restrict__ a_buf, float* __restrict__ b_buf) {
  const int dir = (blockIdx.x >> 2) & 1;
  const int b   = ((blockIdx.x >> 3) << 2) | (blockIdx.x & 3);
  const int tid = threadIdx.x;
  const int wf  = tid >> 6;                  // 0..15
  const bool pri = wf < 8;
  const int lane = tid & 63;
  const int w8   = wf & 7;
  const int tile = (w8 < 4) ? w8 : (11 - w8);
  const int myk  = tile * 64 + lane;

  __shared__ uint4 stg[16][8][64];               // 128 KB staging rings
  __shared__ __align__(16) ushort_t wpk[512];
  __shared__ float cs3[3 * S1_];
  __shared__ float zl[S1_];
  __shared__ float mshl[512];
  __shared__ float psum[512];
  __shared__ float tmaxs[2][9];                  // parity double-buffered
  __shared__ float red[8];
  __shared__ int   pat[LP_];

  for (int i = tid; i < 3 * S1_; i += 1024) cs3[i] = cs[b * 3 * S1_ + i];
  if (tid < LP_) pat[tid] = pattern[tid];
  const int myls = ls[b];

  // wave-uniform subtile schedule
  int nsub;
  if (!dir) nsub = pri ? ((tile + 1) >> 1) : ((tile >> 1) + 1);
  else      nsub = pri ? ((8 - tile) >> 1) : (((7 - tile) >> 1) + 1);
  const int nit = nsub * 8;
  auto SUB = [&](int si) -> int {
    if (!dir) return pri ? (si << 1) : (((si << 1) + 1 < tile) ? ((si << 1) + 1) : tile);
    return pri ? (tile + 1 + (si << 1)) : (si == 0 ? tile : tile + (si << 1));
  };

  float* obuf = dir ? b_buf : a_buf;
  float areg = NEG, areg512 = NEG;
  if (pri) {
    const int initk = dir ? myls : 0;
    areg    = (myk == initk) ? 0.0f : NEG;
    areg512 = (dir && myls == 512) ? 0.0f : NEG;
    const int row0 = dir ? LP_ : 0;
    float* orow = obuf + (b * (LP_ + 1) + row0) * S1_;
    orow[myk] = areg;
    if (tid == 0) orow[512] = areg512;
  }
  __syncthreads();

  for (int s = 0; s < LP_; ++s) {
    const int c = pat[dir ? (LP_ - 1 - s) : s];
    const float* csr = cs3 + c * S1_;
    const uint4* Ecf = Efo + (size_t)c * 64 * 513;
    const uint4* Ecb = Ebo + (size_t)c * 65 * 512;
    float* tmx = tmaxs[s & 1];
    const uint4* wq = (const uint4*)wpk;

    auto ISSUE = [&](int i) {
      const int t = SUB(i >> 3);
      const int o = t * 8 + (i & 7);
      const uint4* gsrc = (dir ? (Ecb + o * 512) : (Ecf + o * 513)) + tile * 64 + lane;
      stage16(gsrc, &stg[wf][i & 7][0], lane);
    };

    // early async staging (overlaps phases 1-3)
    if (nit) {
      #pragma unroll
      for (int i = 0; i < 8; ++i) ISSUE(i);
    }

    float pfx = NINF, tmax = 0.f, z = 0.f;
    if (pri) {
      const float mycs = csr[myk];
      z = areg + (dir ? mycs : -mycs);
      zl[myk] = z;
      pfx = z;
      if (!dir) {
        #pragma unroll
        for (int d = 1; d < 64; d <<= 1) {
          float o = __shfl_up(pfx, d);
          if (lane >= d) pfx = fmaxf(pfx, o);
        }
        tmax = __shfl(pfx, 63);
        if (lane == 63) tmx[tile] = pfx;
      } else {
        #pragma unroll
        for (int d = 1; d < 64; d <<= 1) {
          float o = __shfl_down(pfx, d);
          if (lane < 64 - d) pfx = fmaxf(pfx, o);
        }
        tmax = __shfl(pfx, 0);
        if (lane == 0) tmx[tile] = pfx;
        if (tid == 0) tmx[8] = areg512 + csr[512];
      }
    }
    sync_lgkm();                                   // barrier A

    float msh = 0.f;
    if (pri) {
      if (!dir) {
        float off = NINF;
        for (int t2 = 0; t2 < tile; ++t2) off = fmaxf(off, tmx[t2]);
        float p1 = __shfl_up(pfx, 1);
        msh = fmaxf((lane == 0) ? NINF : p1, off);
      } else {
        float off = tmx[8];
        for (int t2 = tile + 1; t2 < 8; ++t2) off = fmaxf(off, tmx[t2]);
        float p1 = __shfl_down(pfx, 1);
        msh = fmaxf((lane == 63) ? NINF : p1, off);
      }
      mshl[myk] = msh;
      wpk[myk] = f2bf(exp2f((z - tmax) * L2E));
    }
    sync_lgkm();                                   // barrier B
    if (!pri) msh = mshl[myk];

    // ---- pipelined consume ----
    float acc = 0.f, sub0 = 0.f, sub1 = 0.f, sub2 = 0.f, sub3 = 0.f;
    auto CONSUME = [&](int i) {
      const int si = i >> 3, r = i & 7;
      const int t = SUB(si);
      uint4 e = stg[wf][i & 7][lane];
      const bool isd = (!pri) && (dir ? (si == 0) : (si == nsub - 1));
      if (!isd) {
        uint4 w4 = wq[t * 8 + r];
        sub0 = dot2p(e.x, w4.x, sub0);
        sub1 = dot2p(e.y, w4.y, sub1);
        sub2 = dot2p(e.z, w4.z, sub2);
        sub3 = dot2p(e.w, w4.w, sub3);
        if (r == 7) {
          acc += exp2f((tmx[t] - msh) * L2E) * ((sub0 + sub1) + (sub2 + sub3));
          sub0 = sub1 = sub2 = sub3 = 0.f;
        }
      } else {
        const float* zp = zl + tile * 64;
        uint_t ew[4] = {e.x, e.y, e.z, e.w};
        #pragma unroll
        for (int rr = 0; rr < 8; ++rr) {
          int jl = r * 8 + rr;
          bool live = dir ? (jl > lane) : (jl < lane);
          float a = live ? (zp[jl] - msh) : NEG;
          acc += bf2f((ushort_t)(ew[rr >> 1] >> ((rr & 1) * 16))) * exp2f(a * L2E);
        }
      }
    };

    for (int i = 0; i + 8 < nit; ++i) {
      wait_vm(7);
      CONSUME(i);
      ISSUE(i + 8);
    }
    if (nit) {
      const int base = nit - 8;
      #pragma unroll
      for (int j = 0; j < 8; ++j) {
        wait_vm(7 - j);
        CONSUME(base + j);
      }
    }

    // ---- post-pipeline extras (window B..C: tmx reads safe) ----
    float msh512 = NINF;
    if (!dir) {
      if (pri) {
        msh512 = tmx[0];
        #pragma unroll
        for (int t2 = 1; t2 < 8; ++t2) msh512 = fmaxf(msh512, tmx[t2]);
        float e512 = bf2f(((const ushort_t*)(Ecf + (tid >> 3) * 513 + 512))[tid & 7]);
        float p = e512 * bf2f(wpk[tid]) * exp2f((tmx[tid >> 6] - msh512) * L2E);
        #pragma unroll
        for (int o = 1; o < 64; o <<= 1) p += __shfl_xor(p, o);
        if (lane == 0) red[w8] = p;
      } else {
        psum[myk] = acc;
      }
    } else {
      if (!pri) {
        acc += bf2f(((const ushort_t*)(Ecb + 64 * 512 + myk))[0]) *
               exp2f((tmx[8] - msh) * L2E);
        psum[myk] = acc;
      }
    }
    sync_lgkm();                                   // barrier C

    if (pri) {
      acc += psum[myk];
      if (!dir) {
        float ar = (acc > 0.0f) ? (csr[myk] + msh + log2f(acc) * LN2f) : NEG;
        areg = ar;
        float* orow = obuf + (b * (LP_ + 1) + (s + 1)) * S1_;
        orow[myk] = ar;
        if (tid == 0) {
          float t2s = ((red[0] + red[1]) + (red[2] + red[3])) +
                      ((red[4] + red[5]) + (red[6] + red[7]));
          areg512 = (t2s > 0.0f) ? (csr[512] + msh512 + log2f(t2s) * LN2f) : NEG;
          orow[512] = areg512;
        }
      } else {
        float ar = (acc > 0.0f) ? (msh - csr[myk] + log2f(acc) * LN2f) : NEG;
        areg = ar;
        float* orow = obuf + (b * (LP_ + 1) + (LP_ - 1 - s)) * S1_;
        orow[myk] = ar;
        if (tid == 0) { areg512 = NEG; orow[512] = NEG; }
      }
    }
  }
}

// ---------------- epilogue ----------------
__global__ void k_out(const float* __restrict__ a_buf, const float* __restrict__ b_buf,
                      const int* __restrict__ ls, float* __restrict__ out) {
  const int TOT = B_ * (LP_ + 1) * S1_;
  int idx = blockIdx.x * 256 + threadIdx.x;
  if (idx >= TOT) return;
  int b = idx / ((LP_ + 1) * S1_);
  float M = a_buf[(b * (LP_ + 1) + LP_) * S1_ + ls[b]];
  out[idx] = a_buf[idx] + b_buf[idx] - M;
}

// ---------------- launcher ----------------
extern "C" void kernel_launch(void* const* d_in, const int* in_sizes, int n_in,
                              void* d_out, int out_size, void* d_ws, size_t ws_size,
                              hipStream_t stream) {
  const float* ss3     = (const float*)d_in[0];
  const float* Q       = (const float*)d_in[1];
  const int*   pattern = (const int*)d_in[2];
  const int*   ls      = (const int*)d_in[3];
  float* out = (float*)d_out;

  float* ws    = (float*)d_ws;
  float* cs    = ws;                                    // B*3*S1 floats
  float* a_buf = cs + B_ * 3 * S1_;                     // B*(LP+1)*S1
  float* b_buf = a_buf + B_ * (LP_ + 1) * S1_;
  uint4* Efo = (uint4*)(b_buf + B_ * (LP_ + 1) * S1_);  // 3*64*513 uint4
  uint4* Ebo = Efo + 3 * 64 * 513;                      // 3*65*512 uint4

  k_cumsum<<<dim3(B_, 3), 512, 0, stream>>>(ss3, cs);
  k_prep  <<<dim3(9, 8, 3), dim3(64, 8), 0, stream>>>(Q, Efo, Ebo);
  k_scan  <<<2 * B_, 1024, 0, stream>>>(Efo, Ebo, cs, pattern, ls, a_buf, b_buf);

  const int TOT = B_ * (LP_ + 1) * S1_;
  k_out<<<(TOT + 255) / 256, 256, 0, stream>>>(a_buf, b_buf, ls, out);
}